// Round 9
// baseline (228.834 us; speedup 1.0000x reference)
//
#include <hip/hip_runtime.h>
#include <math.h>

#define N_     325
#define BN_    10400
#define OUTSZ_ (BN_*12)   // 124800
#define RB_    208        // rows per block (13 waves x 16)
#define WV_    13
#define THR_   832

// R21 structure: R20 with LDS cut 71296 -> 65088 B (<= 64 KiB) to get TWO
// 13-wave blocks per CU. Evidence for the 128-KiB schedulable-LDS/CU cap:
// R17 (53.2KB) predicted-vs-measured occ 42/41.9%; R18-20 (70-71.7KB) 33/33%.
// Cuts: (1) h-plane pad removed -- stride 144->128 with col-block swizzle
// (phys col-block = ct ^ (row&3)): reads stay conflict-free (8 lanes per 16B
// position), writes keep compile-time immediate offsets i*128+((ct^i)<<5);
// (2) linW frags 2048->128 B (depend only on kg,ch; broadcast reads);
// (3) decoder-only LW + lv-broadcast overlaid onto the dead X region.
// Everything else identical to R20 (reg diet, sched_barrier, one-round grid).

typedef _Float16 h8v  __attribute__((ext_vector_type(8)));  // 8 f16 (4 VGPRs)
typedef float    f4v  __attribute__((ext_vector_type(4)));  // 4 fp32 acc
typedef unsigned int u32x4 __attribute__((ext_vector_type(4)));

#define L1C 1.4426950408889634f    // log2(e)
#define L2C 2.8853900817779268f    // 2*log2(e)

__device__ __forceinline__ float rcp_f(float x){ return __builtin_amdgcn_rcpf(x); }
#if __has_builtin(__builtin_amdgcn_exp2f)
__device__ __forceinline__ float exp2_f(float x){ return __builtin_amdgcn_exp2f(x); }
#else
__device__ __forceinline__ float exp2_f(float x){ return __expf(x * 0.6931471805599453f); }
#endif

__device__ __forceinline__ unsigned short f16u(float x){
    union { _Float16 h; unsigned short u; } cv; cv.h = (_Float16)x; return cv.u;
}

// ---------------- LDS layout (bytes) ----------------
// [BOFF,  +24576) 24 main B frags: f*1024 + lane*16 (shared by 13 waves)
// [EOFF,  +3072 ) 12 ext  B frags: e*256 + (lane&15)*16
// [HOFF,  +26624) per-wave h plane: w*2048; 16 rows x 128 B, col-block-swizzled:
//                 phys byte = row*128 + ((blk ^ (row&3))<<5) + (b&31), blk=b>>5
// [XOFF,  +9984 ) x packed f16 pair: row*48 + t*4   (encoder only)
// [LWOFF, +128  ) dec linW frags (overlay on X): ch*64 + kg*16
// [LOFF,  +832  ) dec lv broadcast (overlay on X): w*64 + idx*4
// [WOFF,  +832  ) softmax weight per row
#define BOFF   0
#define EOFF   24576
#define HOFF   27648
#define XOFF   54272
#define LWOFF  54272
#define LOFF   54400
#define WOFF   64256
#define SMEMSZ 65088      // x2 = 130176 <= 131072 -> 2 blocks/CU

#define MFMA(A,B,C) __builtin_amdgcn_mfma_f32_16x16x32_f16((A),(B),(C),0,0,0)

// Stage 192x64 f32 Whh (one cluster) into 24 pre-swizzled f16 B-frags, scaled:
// r,z rows by -log2e; n rows by -2log2e. CONFLICT-FREE: thread writes one full
// 16-B block at linearly increasing LDS address. Frag mapping preserved:
// frag f = g*8+ct*2+ch; lane (kg*16+l15) holds col=ct*16+l15, k=ch*32+kg*8+j.
__device__ __forceinline__ void stage_main(const float* __restrict__ W, char* smem, int tid)
{
#pragma unroll
    for (int it = 0; it < 2; ++it) {
        int a16 = it*THR_ + tid;           // 16-B block index in [0,1536)
        if (a16 < 1536) {
            int f     = a16 >> 6;          // frag 0..23
            int lanew = a16 & 63;          // dest lane slot
            int colf  = lanew & 15;
            int kb4   = lanew >> 4;
            int ch    = f & 1;
            int ct    = (f >> 1) & 3;
            int g     = f >> 3;
            int gc    = g*64 + ct*16 + colf;   // weight row 0..191
            int k0    = ch*32 + kb4*8;
            float sc  = (g < 2) ? -L1C : -L2C;
            const float* p = W + gc*64 + k0;
            float4 a = *(const float4*)p;
            float4 b = *(const float4*)(p+4);
            h8v v;
            v[0]=(_Float16)(sc*a.x); v[1]=(_Float16)(sc*a.y);
            v[2]=(_Float16)(sc*a.z); v[3]=(_Float16)(sc*a.w);
            v[4]=(_Float16)(sc*b.x); v[5]=(_Float16)(sc*b.y);
            v[6]=(_Float16)(sc*b.z); v[7]=(_Float16)(sc*b.w);
            *(h8v*)(smem + BOFF + a16*16) = v;
        }
    }
}

// One recurrence step for one wave: 36 MFMA + gate algebra, 16 rows x 64 cols.
// wb = h-plane write base (hp + kg*512 + l15*2); write offset i*128+((ct^i)<<5)
// implements the col-block swizzle with compile-time immediates.
__device__ __forceinline__ void rnn_step(h8v Aeh, h8v Ah0, h8v Ah1,
                                         const char* bb, const char* eb,
                                         const float cbh[4], float (&hreg)[4][4],
                                         char* wb)
{
    const f4v Z0 = {0.f,0.f,0.f,0.f};
#pragma unroll
    for (int ct = 0; ct < 4; ++ct) {
        f4v a0 = MFMA(Aeh, *(const h8v*)(eb + ct*256),       Z0);   // r: ext (Wih,b)
        a0 = MFMA(Ah0, *(const h8v*)(bb + (ct*2   )*1024), a0);     // r: Whh ch0
        a0 = MFMA(Ah1, *(const h8v*)(bb + (ct*2+1 )*1024), a0);     // r: Whh ch1
        f4v a1 = MFMA(Aeh, *(const h8v*)(eb + (4+ct)*256),   Z0);   // z
        a1 = MFMA(Ah0, *(const h8v*)(bb + (8+ct*2 )*1024), a1);
        a1 = MFMA(Ah1, *(const h8v*)(bb + (9+ct*2 )*1024), a1);
        f4v a3 = MFMA(Aeh, *(const h8v*)(eb + (8+ct)*256),   Z0);   // n: gi part
        f4v a2 = MFMA(Ah0, *(const h8v*)(bb + (16+ct*2)*1024), Z0); // n: Whh.h
        a2 = MFMA(Ah1, *(const h8v*)(bb + (17+ct*2)*1024), a2);
#pragma unroll
        for (int i = 0; i < 4; ++i) {
            float er = exp2_f(a0[i]);
            float rr = rcp_f(1.0f + er);
            float ez = exp2_f(a1[i]);
            float en = exp2_f(fmaf(rr, a2[i] + cbh[ct], a3[i]));
            float h  = hreg[ct][i];
            float aa = 1.0f + ez;
            float den = fmaf(en, aa, aa);        // (1+en)(1+ez)
            float t1  = fmaf(-en, ez, ez);       // ez(1-en)
            float t2  = fmaf(en, h, h);          // h(1+en)
            float hnew = (t1 + t2) * rcp_f(den);
            hreg[ct][i] = hnew;
            *(_Float16*)(wb + i*128 + ((ct^i)<<5)) = (_Float16)hnew;
        }
        __builtin_amdgcn_sched_barrier(0);       // no cross-ct acc overlap
    }
}

__global__ void __launch_bounds__(THR_, 8) krnn_kernel(
    const float* __restrict__ X,
    const float* __restrict__ eWih, const float* __restrict__ eWhh,
    const float* __restrict__ ebih, const float* __restrict__ ebhh,
    const float* __restrict__ dWih, const float* __restrict__ dWhh,
    const float* __restrict__ dbih, const float* __restrict__ dbhh,
    const float* __restrict__ linW, const float* __restrict__ linb,
    const float* __restrict__ embed, float* __restrict__ ws)
{
    __shared__ __align__(16) char smem[SMEMSZ];

    const int c    = blockIdx.y;
    const int row0 = blockIdx.x * RB_;          // 208 rows per block
    const int tid  = threadIdx.x;
    const int lane = tid & 63;
    const int w    = tid >> 6;                  // wave 0..12
    const int l15  = lane & 15;
    const int kg   = lane >> 4;

    // ---------------- stage encoder weights / x / softmax / h=0 ----------------
    stage_main(eWhh + c*12288, smem, tid);

    if (tid < 192) {                            // enc ext: k0=Wih0,k1=Wih1,k2=bias
        int e = tid >> 4, ln = tid & 15;
        int g = e >> 2, ct = e & 3;
        int gc = g*64 + ct*16 + ln;
        float sc = (g < 2) ? -L1C : -L2C;
        float w0 = eWih[c*384 + gc*2], w1 = eWih[c*384 + gc*2 + 1];
        float bb_ = (g < 2) ? (ebih[c*192+gc] + ebhh[c*192+gc]) : ebih[c*192+gc];
        unsigned short* d = (unsigned short*)(smem + EOFF + e*256 + ln*16);
        d[0] = f16u(sc*w0); d[1] = f16u(sc*w1); d[2] = f16u(sc*bb_);
        d[3]=0; d[4]=0; d[5]=0; d[6]=0; d[7]=0;
    }
    for (int i = tid; i < RB_*12; i += THR_) {  // x: packed f16 (x0,x1) per (row,t)
        int r = i / 12, t = i - r*12;
        int rg = row0 + r;
        const float* p = X + (size_t)rg*24 + t*2;
        unsigned v = (unsigned)f16u(p[0]) | ((unsigned)f16u(p[1]) << 16);
        *(unsigned*)(smem + XOFF + r*48 + t*4) = v;
    }
    if (tid < RB_) {                            // softmax weight per row
        int r = row0 + tid;
        int n = r % N_;
        float e[10], mx = -1e30f;
#pragma unroll
        for (int cc=0; cc<10; ++cc){ e[cc]=embed[n*10+cc]; mx=fmaxf(mx,e[cc]); }
        float den = 0.0f;
#pragma unroll
        for (int cc=0; cc<10; ++cc) den += exp2_f((e[cc]-mx)*L1C);
        *(float*)(smem + WOFF + tid*4) = exp2_f((e[c]-mx)*L1C) * rcp_f(den);
    }
    for (int i = tid; i < WV_*512; i += THR_)   // zero all 13 h planes
        *(unsigned*)(smem + HOFF + i*4) = 0u;

    float cbh[4];                               // n-gate bhh per owned col (fp32)
#pragma unroll
    for (int ct=0; ct<4; ++ct) cbh[ct] = -L2C * ebhh[c*192 + 128 + l15 + 16*ct];

    __syncthreads();                            // barrier 1/3

    char* hp = smem + HOFF + w*2048;            // private h plane
    // read offsets: row l15, logical bytes kg*16 (+64 for ch1), col-block swz
    const int rdo0 = l15*128 + ((((kg>>1) ^ (l15&3))<<5) | ((kg&1)<<4));
    const int rdo1 = rdo0 ^ 64;
    char* wb = hp + kg*512 + l15*2;             // gate write base (row kg*4+i)
    const char* bb = smem + lane*16;            // main frag base
    const char* eb = smem + EOFF + l15*16;      // ext frag base (broadcast reads)

    float hreg[4][4];
#pragma unroll
    for (int ct=0; ct<4; ++ct)
#pragma unroll
        for (int i=0;i<4;++i) hreg[ct][i] = 0.0f;

    // ---------------- encoder: 12 barrier-free steps ----------------
    for (int t = 0; t < 12; ++t) {
        unsigned xd = *(const unsigned*)(smem + XOFF + (w*16 + l15)*48 + t*4);
        union { u32x4 u; h8v h; } ae;
        ae.u.x = (lane < 16) ? xd : 0u;         // k0=x0, k1=x1
        ae.u.y = (lane < 16) ? 0x00003C00u : 0u;// k2=1.0
        ae.u.z = 0u; ae.u.w = 0u;
        h8v Ah0 = *(const h8v*)(hp + rdo0);
        h8v Ah1 = *(const h8v*)(hp + rdo1);
        rnn_step(ae.h, Ah0, Ah1, bb, eb, cbh, hreg, wb);
    }

    // lv0 = f16(x[t=11].x) packed with 1.0 for the dec A-ext, before overlay
    unsigned aew = (*(const unsigned*)(smem + XOFF + (w*16 + l15)*48 + 44) & 0xFFFFu)
                   | 0x3C000000u;

    __syncthreads();                            // barrier 2/3 (all enc reads done)

    // ---------------- stage decoder weights ----------------
    stage_main(dWhh + c*12288, smem, tid);
    if (tid < 192) {                            // dec ext: k0=Wih, k1=bias
        int e = tid >> 4, ln = tid & 15;
        int g = e >> 2, ct = e & 3;
        int gc = g*64 + ct*16 + ln;
        float k0, k1;
        if (g < 2) { k0 = -L1C*dWih[c*192+gc]; k1 = -L1C*(dbih[c*192+gc]+dbhh[c*192+gc]); }
        else       { k0 = -L2C*dWih[c*192+gc]; k1 = -L2C*dbih[c*192+gc]; }
        unsigned short* d = (unsigned short*)(smem + EOFF + e*256 + ln*16);
        d[0] = f16u(k0); d[1] = f16u(k1);
        d[2]=0; d[3]=0; d[4]=0; d[5]=0; d[6]=0; d[7]=0;
    }
    if (tid < 8) {                              // linW frags, compressed [ch][kg]
        int ch = tid >> 2, k4 = tid & 3;
        unsigned short* d = (unsigned short*)(smem + LWOFF + ch*64 + k4*16);
#pragma unroll
        for (int j=0;j<8;++j) d[j] = f16u(linW[c*64 + ch*32 + k4*8 + j]);
    }
#pragma unroll
    for (int ct=0; ct<4; ++ct) cbh[ct] = -L2C * dbhh[c*192 + 128 + l15 + 16*ct];
    const float lb = linb[c];
    float* __restrict__ wsc = ws + (size_t)c * OUTSZ_;

    __syncthreads();                            // barrier 3/3

    // ---------------- decoder: 12 barrier-free steps ----------------
    for (int s = 0; s < 12; ++s) {
        h8v Ah0 = *(const h8v*)(hp + rdo0);
        h8v Ah1 = *(const h8v*)(hp + rdo1);
        if (s > 0) {
            const f4v Zv = {0.f,0.f,0.f,0.f};
            f4v av = MFMA(Ah0, *(const h8v*)(smem + LWOFF + kg*16), Zv);
            av = MFMA(Ah1, *(const h8v*)(smem + LWOFF + 64 + kg*16), av);
            if (l15 == 0) {                     // lanes l15==0 own rows kg*4+i
#pragma unroll
                for (int i=0;i<4;++i) {
                    float lv = av[i] + lb;      // v_{s-1}
                    *(float*)(smem + LOFF + w*64 + (kg*4+i)*4) = lv;
                    int r = row0 + w*16 + kg*4 + i;
                    float wg = *(const float*)(smem + WOFF + (w*16 + kg*4 + i)*4);
                    wsc[(size_t)r*12 + (s-1)] = wg*lv;
                }
            }
            float lvme = *(const float*)(smem + LOFF + w*64 + l15*4); // intra-wave
            aew = (unsigned)f16u(lvme) | 0x3C000000u;   // k0=lv, k1=1.0
        }
        union { u32x4 u; h8v h; } ae;
        ae.u.x = (lane < 16) ? aew : 0u;
        ae.u.y = 0u; ae.u.z = 0u; ae.u.w = 0u;
        rnn_step(ae.h, Ah0, Ah1, bb, eb, cbh, hreg, wb);
    }

    // ---------------- epilogue: v_11 from h_11 ----------------
    {
        h8v Ah0 = *(const h8v*)(hp + rdo0);
        h8v Ah1 = *(const h8v*)(hp + rdo1);
        const f4v Zv = {0.f,0.f,0.f,0.f};
        f4v av = MFMA(Ah0, *(const h8v*)(smem + LWOFF + kg*16), Zv);
        av = MFMA(Ah1, *(const h8v*)(smem + LWOFF + 64 + kg*16), av);
        if (l15 == 0) {
#pragma unroll
            for (int i=0;i<4;++i) {
                float lv = av[i] + lb;
                int r = row0 + w*16 + kg*4 + i;
                float wg = *(const float*)(smem + WOFF + (w*16 + kg*4 + i)*4);
                wsc[(size_t)r*12 + 11] = wg*lv;
            }
        }
    }
}

// Mix over clusters: out[i] = sum_c ws[c][i]. ws is 5 MB, L2/L3-hot.
__global__ void __launch_bounds__(256) mix_kernel(const float* __restrict__ ws,
                                                  float* __restrict__ out)
{
    int i = blockIdx.x * 256 + threadIdx.x;
    if (i < OUTSZ_) {
        float s = 0.0f;
#pragma unroll
        for (int c = 0; c < 10; ++c) s += ws[(size_t)c * OUTSZ_ + i];
        out[i] = s;
    }
}

extern "C" void kernel_launch(void* const* d_in, const int* in_sizes, int n_in,
                              void* d_out, int out_size, void* d_ws, size_t ws_size,
                              hipStream_t stream) {
    // 0:A 1:X 2:enc_Wih 3:enc_Whh 4:enc_bih 5:enc_bhh
    // 6:dec_Wih 7:dec_Whh 8:dec_bih 9:dec_bhh 10:lin_W 11:lin_b 12:embed
    const float* X    = (const float*)d_in[1];
    const float* eWih = (const float*)d_in[2];
    const float* eWhh = (const float*)d_in[3];
    const float* ebih = (const float*)d_in[4];
    const float* ebhh = (const float*)d_in[5];
    const float* dWih = (const float*)d_in[6];
    const float* dWhh = (const float*)d_in[7];
    const float* dbih = (const float*)d_in[8];
    const float* dbhh = (const float*)d_in[9];
    const float* linW = (const float*)d_in[10];
    const float* linb = (const float*)d_in[11];
    const float* emb  = (const float*)d_in[12];
    float* ws  = (float*)d_ws;
    float* out = (float*)d_out;

    dim3 grid(BN_ / RB_, 10);   // 50 x 10 = 500 blocks; 2/CU -> ONE round
    krnn_kernel<<<grid, dim3(THR_), 0, stream>>>(
        X, eWih, eWhh, ebih, ebhh, dWih, dWhh, dbih, dbhh, linW, linb, emb, ws);
    mix_kernel<<<(OUTSZ_ + 255) / 256, dim3(256), 0, stream>>>(ws, out);
}